// Round 1
// baseline (92635.913 us; speedup 1.0000x reference)
//
#include <hip/hip_runtime.h>

#define BB   128   // batch
#define TT   1024  // time steps
#define INP  256   // input dim
#define HH   512   // hidden dim
#define OUTD 256   // output dim

#define GB 16              // batches per group
#define NGROUPS 8          // 128 / 16
#define BLKS_PER_GROUP 32  // j-tiles of 16 covering H=512
#define NBLK (NGROUPS * BLKS_PER_GROUP)  // 256 blocks

__device__ __forceinline__ float dot4(const float4 a, const float4 b, float acc) {
  acc = fmaf(a.x, b.x, acc);
  acc = fmaf(a.y, b.y, acc);
  acc = fmaf(a.z, b.z, acc);
  acc = fmaf(a.w, b.w, acc);
  return acc;
}

// Monotonic-counter group barrier: no reset, no sense flag. target = nblk*phase.
__device__ __forceinline__ void group_barrier(unsigned* cnt, unsigned target) {
  __syncthreads();
  if (threadIdx.x == 0) {
    __hip_atomic_fetch_add(cnt, 1u, __ATOMIC_RELEASE, __HIP_MEMORY_SCOPE_AGENT);
    while (__hip_atomic_load(cnt, __ATOMIC_ACQUIRE, __HIP_MEMORY_SCOPE_AGENT) < target) {
      __builtin_amdgcn_s_sleep(8);
    }
  }
  __syncthreads();
}

__global__ void __launch_bounds__(256) rnn_persistent(
    const float* __restrict__ x,       // [B][T][IN]
    const float* __restrict__ h0init,  // [2][B][H]
    const float* __restrict__ w_ih0,   // [H][IN]
    const float* __restrict__ w_hh0,   // [H][H]
    const float* __restrict__ b_ih0,   // [H]
    const float* __restrict__ b_hh0,   // [H]
    const float* __restrict__ w_ih1,   // [H][H]
    const float* __restrict__ w_hh1,   // [H][H]
    const float* __restrict__ b_ih1,   // [H]
    const float* __restrict__ b_hh1,   // [H]
    const float* __restrict__ fc_w,    // [OUT][H]
    const float* __restrict__ fc_b,    // [OUT]
    float* __restrict__ out,           // [B][OUT]
    unsigned* __restrict__ bar,        // NGROUPS counters, 64B apart
    float* __restrict__ h0buf,         // [2][B][H] double buffer
    float* __restrict__ h1buf)         // [2][B][H] double buffer
{
  const int g   = blockIdx.x & (NGROUPS - 1);  // group -> same XCD (blockIdx % 8)
  const int s   = blockIdx.x >> 3;             // j-tile 0..31
  const int tid = threadIdx.x;
  const int tb  = tid & (GB - 1);              // batch within group 0..15
  const int tj  = tid >> 4;                    // j within tile 0..15
  const int b   = g * GB + tb;                 // global batch
  const int j   = s * 16 + tj;                 // global hidden index

  unsigned* cnt = bar + g * 16;  // 64B spacing between group counters
  unsigned phase = 0;

  const float bias0 = b_ih0[j] + b_hh0[j];
  const float bias1 = b_ih1[j] + b_hh1[j];

  const float4* w0i = (const float4*)(w_ih0 + (size_t)j * INP);
  const float4* w0h = (const float4*)(w_hh0 + (size_t)j * HH);
  const float4* w1i = (const float4*)(w_ih1 + (size_t)j * HH);
  const float4* w1h = (const float4*)(w_hh1 + (size_t)j * HH);

  for (int t = 0; t < TT; ++t) {
    // ---------------- layer 0: h0n = tanh(x_t W_ih0^T + h0 W_hh0^T + bias0)
    const float4* xv = (const float4*)(x + ((size_t)b * TT + (size_t)t) * INP);
    const float* h0p_f = (t == 0)
        ? (h0init + (size_t)b * HH)
        : (h0buf + (size_t)((t - 1) & 1) * (BB * HH) + (size_t)b * HH);
    const float4* h0p = (const float4*)h0p_f;

    float acc = bias0;
    #pragma unroll 8
    for (int k = 0; k < INP / 4; ++k) acc = dot4(xv[k], w0i[k], acc);
    #pragma unroll 8
    for (int k = 0; k < HH / 4; ++k) acc = dot4(h0p[k], w0h[k], acc);
    const float h0n = tanhf(acc);
    h0buf[(size_t)(t & 1) * (BB * HH) + (size_t)b * HH + j] = h0n;

    ++phase;
    group_barrier(cnt, (unsigned)(BLKS_PER_GROUP) * phase);

    // ---------------- layer 1: h1n = tanh(h0n W_ih1^T + h1 W_hh1^T + bias1)
    const float4* h0c = (const float4*)(h0buf + (size_t)(t & 1) * (BB * HH) + (size_t)b * HH);
    const float* h1p_f = (t == 0)
        ? (h0init + (size_t)(BB * HH) + (size_t)b * HH)
        : (h1buf + (size_t)((t - 1) & 1) * (BB * HH) + (size_t)b * HH);
    const float4* h1p = (const float4*)h1p_f;

    float acc1 = bias1;
    #pragma unroll 8
    for (int k = 0; k < HH / 4; ++k) acc1 = dot4(h0c[k], w1i[k], acc1);
    #pragma unroll 8
    for (int k = 0; k < HH / 4; ++k) acc1 = dot4(h1p[k], w1h[k], acc1);
    const float h1n = tanhf(acc1);
    h1buf[(size_t)(t & 1) * (BB * HH) + (size_t)b * HH + j] = h1n;

    ++phase;
    group_barrier(cnt, (unsigned)(BLKS_PER_GROUP) * phase);
  }

  // ---------------- FC epilogue: out = h1_final @ fc_w^T + fc_b
  // (T-1)&1 == 1 since T=1024. Block (g,s) covers batches of group g x o-tile of 8.
  if (tid < 128) {
    const int o = s * 8 + (tid >> 4);  // tid>>4 in 0..7
    const float4* hrow = (const float4*)(h1buf + (size_t)1 * (BB * HH) + (size_t)b * HH);
    const float4* wrow = (const float4*)(fc_w + (size_t)o * HH);
    float acc = fc_b[o];
    #pragma unroll 8
    for (int k = 0; k < HH / 4; ++k) acc = dot4(hrow[k], wrow[k], acc);
    out[(size_t)b * OUTD + o] = acc;
  }
}

extern "C" void kernel_launch(void* const* d_in, const int* in_sizes, int n_in,
                              void* d_out, int out_size, void* d_ws, size_t ws_size,
                              hipStream_t stream) {
  (void)in_sizes; (void)n_in; (void)out_size; (void)ws_size;

  const float* x      = (const float*)d_in[0];
  const float* h0init = (const float*)d_in[1];
  const float* w_ih0  = (const float*)d_in[2];
  const float* w_hh0  = (const float*)d_in[3];
  const float* b_ih0  = (const float*)d_in[4];
  const float* b_hh0  = (const float*)d_in[5];
  const float* w_ih1  = (const float*)d_in[6];
  const float* w_hh1  = (const float*)d_in[7];
  const float* b_ih1  = (const float*)d_in[8];
  const float* b_hh1  = (const float*)d_in[9];
  const float* fc_w   = (const float*)d_in[10];
  const float* fc_b   = (const float*)d_in[11];
  float* out = (float*)d_out;

  // ws layout: [0,4096) barrier counters (zeroed); then h0buf[2][B][H]; h1buf[2][B][H]
  unsigned* bar = (unsigned*)d_ws;
  float* h0buf = (float*)((char*)d_ws + 4096);
  float* h1buf = h0buf + 2 * BB * HH;

  hipMemsetAsync(d_ws, 0, 4096, stream);

  rnn_persistent<<<dim3(NBLK), dim3(256), 0, stream>>>(
      x, h0init, w_ih0, w_hh0, b_ih0, b_hh0, w_ih1, w_hh1, b_ih1, b_hh1,
      fc_w, fc_b, out, bar, h0buf, h1buf);
}

// Round 2
// 6603.495 us; speedup vs baseline: 14.0283x; 14.0283x over previous
//
#include <hip/hip_runtime.h>

#define BB   128   // batch
#define TT   1024  // time steps
#define INP  256   // input dim
#define HH   512   // hidden dim
#define OUTD 256   // output dim
#define GB   16    // batches per group
#define NG   8     // groups (one per XCD via blockIdx%8)
#define NBLK 128   // 8 groups x (8 L0-blocks + 8 L1-blocks)

typedef float  f32x4  __attribute__((ext_vector_type(4)));
typedef short  short8 __attribute__((ext_vector_type(8)));

__device__ __forceinline__ unsigned short bf16_rne(float f) {
  union { float f; unsigned u; } v; v.f = f;
  unsigned r = v.u + 0x7fffu + ((v.u >> 16) & 1u);
  return (unsigned short)(r >> 16);
}

// load 8 contiguous fp32 (32B aligned), round-to-nearest-even to 8 bf16
__device__ __forceinline__ short8 load_cvt8(const float* p) {
  const f32x4* q = (const f32x4*)p;
  f32x4 a = q[0], b = q[1];
  union { unsigned short s[8]; short8 v; } u;
  u.s[0] = bf16_rne(a[0]); u.s[1] = bf16_rne(a[1]);
  u.s[2] = bf16_rne(a[2]); u.s[3] = bf16_rne(a[3]);
  u.s[4] = bf16_rne(b[0]); u.s[5] = bf16_rne(b[1]);
  u.s[6] = bf16_rne(b[2]); u.s[7] = bf16_rne(b[3]);
  return u.v;
}

// Monotonic-counter group barrier (16 blocks). Release/acquire at agent scope:
// acquire-load invalidates L1 so post-barrier plain loads see fresh L2 data
// (protocol validated by round-1 pass).
__device__ __forceinline__ void gbar(unsigned* cnt, unsigned target) {
  __syncthreads();
  if (threadIdx.x == 0) {
    __hip_atomic_fetch_add(cnt, 1u, __ATOMIC_RELEASE, __HIP_MEMORY_SCOPE_AGENT);
    while (__hip_atomic_load(cnt, __ATOMIC_ACQUIRE, __HIP_MEMORY_SCOPE_AGENT) < target)
      __builtin_amdgcn_s_sleep(1);
  }
  __syncthreads();
}

// h-state fragment buffers: [buf(2)][group(8)] x [kb(16)][lane(64)][e(8)] bf16.
// Value (b_local, j): kb = j>>5, lane' = ((j>>3)&3)*16 + b_local, e = j&7.
// Reading lane l as MFMA A-operand slot is exactly (kb*64 + l)*8 (lane-contig).
__device__ __forceinline__ unsigned short* hsl(unsigned short* base, int buf, int g) {
  return base + ((size_t)(buf * NG + g)) * (16 * 64 * 8);
}

__global__ void __launch_bounds__(256, 1) rnn_mfma(
    const float* __restrict__ x,       // [B][T][IN]
    const float* __restrict__ h0init,  // [2][B][H]
    const float* __restrict__ w_ih0,   // [H][IN]
    const float* __restrict__ w_hh0,   // [H][H]
    const float* __restrict__ b_ih0,   // [H]
    const float* __restrict__ b_hh0,   // [H]
    const float* __restrict__ w_ih1,   // [H][H]
    const float* __restrict__ w_hh1,   // [H][H]
    const float* __restrict__ b_ih1,   // [H]
    const float* __restrict__ b_hh1,   // [H]
    const float* __restrict__ fc_w,    // [OUT][H]
    const float* __restrict__ fc_b,    // [OUT]
    float* __restrict__ out,           // [B][OUT]
    unsigned* __restrict__ bar,        // NG counters, 64B apart
    unsigned short* __restrict__ h0f,  // h0 frag dbuf
    unsigned short* __restrict__ h1f)  // h1 frag dbuf
{
  const int g    = blockIdx.x & 7;       // group -> XCD locality
  const int role = blockIdx.x >> 3;      // 0..7: layer0 j-tiles, 8..15: layer1
  const bool isL0 = role < 8;
  const int tid  = threadIdx.x;
  const int wv   = tid >> 6;
  const int lane = tid & 63;
  const int ln   = lane & 15;            // A-row (batch) / B-col (j) / D-col
  const int q    = lane >> 4;            // quad
  const int j    = (role & 7) * 64 + wv * 16 + ln;  // this lane's output column
  const int bg   = g * GB;
  unsigned* cnt  = bar + g * 16;
  unsigned phase = 0;

  // ---- init: h0init -> frag buffers, buf 1 (read at first use). Redundant
  // across the group's 16 blocks (identical values; benign).
  for (int c = tid; c < 2048; c += 256) {
    int a  = c >> 10;            // 0 -> h0, 1 -> h1
    int bl = (c >> 6) & 15;
    int j8 = (c & 63) * 8;
    short8 v = load_cvt8(h0init + ((size_t)a * BB + (bg + bl)) * HH + j8);
    unsigned short* dst = hsl(a ? h1f : h0f, 1, g)
        + ((size_t)((j8 >> 5) * 64 + ((j8 >> 3) & 3) * 16 + bl)) * 8;
    *(short8*)dst = v;
  }

  // ---- weight B-fragments -> registers (once). Lane: row j, k = kb*32+q*8+e.
  short8 Bf[32];
  if (isL0) {
#pragma unroll
    for (int kb = 0; kb < 24; ++kb) {
      int k = kb * 32 + q * 8;
      const float* src = (k < INP) ? (w_ih0 + (size_t)j * INP + k)
                                   : (w_hh0 + (size_t)j * HH + (k - INP));
      Bf[kb] = load_cvt8(src);
    }
  } else {
#pragma unroll
    for (int kb = 0; kb < 32; ++kb) {
      int k = kb * 32 + q * 8;
      const float* src = (k < HH) ? (w_ih1 + (size_t)j * HH + k)
                                  : (w_hh1 + (size_t)j * HH + (k - HH));
      Bf[kb] = load_cvt8(src);
    }
  }
  const float bias = isL0 ? (b_ih0[j] + b_hh0[j]) : (b_ih1[j] + b_hh1[j]);

  gbar(cnt, 16 * ++phase);

  // ---- prefetch x fragments for tick 0 (L0 only)
  short8 xa[8];
  if (isL0) {
#pragma unroll
    for (int kb = 0; kb < 8; ++kb)
      xa[kb] = load_cvt8(x + ((size_t)(bg + ln) * TT + 0) * INP + kb * 32 + q * 8);
  }

  const f32x4 z = {0.f, 0.f, 0.f, 0.f};

  // ---- tick loop: at tick t, L0 computes h0(t) (t<T); L1 computes h1(t-1) (t>=1)
  for (int t = 0; t <= TT; ++t) {
    if (isL0) {
      if (t < TT) {
        const unsigned short* hp = hsl(h0f, (t + 1) & 1, g);  // h0(t-1)
        f32x4 ac[4] = {z, z, z, z};
#pragma unroll
        for (int kb = 0; kb < 8; ++kb)
          ac[kb & 3] = __builtin_amdgcn_mfma_f32_16x16x32_bf16(
              xa[kb], Bf[kb], ac[kb & 3], 0, 0, 0);
#pragma unroll
        for (int kb = 8; kb < 24; ++kb) {
          short8 Af = *(const short8*)(hp + ((size_t)(kb - 8) * 64 + lane) * 8);
          ac[kb & 3] = __builtin_amdgcn_mfma_f32_16x16x32_bf16(
              Af, Bf[kb], ac[kb & 3], 0, 0, 0);
        }
        f32x4 d;
        d[0] = ac[0][0] + ac[1][0] + ac[2][0] + ac[3][0];
        d[1] = ac[0][1] + ac[1][1] + ac[2][1] + ac[3][1];
        d[2] = ac[0][2] + ac[1][2] + ac[2][2] + ac[3][2];
        d[3] = ac[0][3] + ac[1][3] + ac[2][3] + ac[3][3];
        unsigned short* wdst = hsl(h0f, t & 1, g);
#pragma unroll
        for (int r = 0; r < 4; ++r) {
          float v = tanhf(d[r] + bias);
          int bl = q * 4 + r;
          wdst[((size_t)((j >> 5) * 64 + ((j >> 3) & 3) * 16 + bl)) * 8 + (j & 7)]
              = bf16_rne(v);
        }
        // prefetch next tick's x before the barrier (overlaps HBM latency)
        if (t + 1 < TT) {
#pragma unroll
          for (int kb = 0; kb < 8; ++kb)
            xa[kb] = load_cvt8(x + ((size_t)(bg + ln) * TT + (t + 1)) * INP
                               + kb * 32 + q * 8);
        }
      }
    } else {
      if (t >= 1) {
        const unsigned short* hp0 = hsl(h0f, (t + 1) & 1, g);  // h0(t-1)
        const unsigned short* hp1 = hsl(h1f, t & 1, g);        // h1(t-2)
        f32x4 ac[4] = {z, z, z, z};
#pragma unroll
        for (int kb = 0; kb < 16; ++kb) {
          short8 Af = *(const short8*)(hp0 + ((size_t)kb * 64 + lane) * 8);
          ac[kb & 3] = __builtin_amdgcn_mfma_f32_16x16x32_bf16(
              Af, Bf[kb], ac[kb & 3], 0, 0, 0);
        }
#pragma unroll
        for (int kb = 16; kb < 32; ++kb) {
          short8 Af = *(const short8*)(hp1 + ((size_t)(kb - 16) * 64 + lane) * 8);
          ac[kb & 3] = __builtin_amdgcn_mfma_f32_16x16x32_bf16(
              Af, Bf[kb], ac[kb & 3], 0, 0, 0);
        }
        f32x4 d;
        d[0] = ac[0][0] + ac[1][0] + ac[2][0] + ac[3][0];
        d[1] = ac[0][1] + ac[1][1] + ac[2][1] + ac[3][1];
        d[2] = ac[0][2] + ac[1][2] + ac[2][2] + ac[3][2];
        d[3] = ac[0][3] + ac[1][3] + ac[2][3] + ac[3][3];
        unsigned short* wdst = hsl(h1f, (t + 1) & 1, g);       // h1(t-1)
#pragma unroll
        for (int r = 0; r < 4; ++r) {
          float v = tanhf(d[r] + bias);
          int bl = q * 4 + r;
          wdst[((size_t)((j >> 5) * 64 + ((j >> 3) & 3) * 16 + bl)) * 8 + (j & 7)]
              = bf16_rne(v);
        }
      }
    }
    gbar(cnt, 16 * ++phase);
  }

  // ---- FC epilogue: out = h1(T-1) @ fc_w^T + fc_b. h1(T-1) is in h1f buf 1.
  // Wave 0 of each block handles o-tile = role*16 for the group's 16 batches.
  if (wv == 0) {
    const unsigned short* hp = hsl(h1f, 1, g);
    const int o = role * 16 + ln;
    f32x4 ac[4] = {z, z, z, z};
#pragma unroll
    for (int kb = 0; kb < 16; ++kb) {
      int k = kb * 32 + q * 8;
      short8 Bfc = load_cvt8(fc_w + (size_t)o * HH + k);
      short8 Af  = *(const short8*)(hp + ((size_t)kb * 64 + lane) * 8);
      ac[kb & 3] = __builtin_amdgcn_mfma_f32_16x16x32_bf16(
          Af, Bfc, ac[kb & 3], 0, 0, 0);
    }
    const float fb = fc_b[o];
#pragma unroll
    for (int r = 0; r < 4; ++r) {
      float v = ac[0][r] + ac[1][r] + ac[2][r] + ac[3][r] + fb;
      out[(size_t)(bg + q * 4 + r) * OUTD + o] = v;
    }
  }
}

extern "C" void kernel_launch(void* const* d_in, const int* in_sizes, int n_in,
                              void* d_out, int out_size, void* d_ws, size_t ws_size,
                              hipStream_t stream) {
  (void)in_sizes; (void)n_in; (void)out_size; (void)ws_size;

  const float* x      = (const float*)d_in[0];
  const float* h0init = (const float*)d_in[1];
  const float* w_ih0  = (const float*)d_in[2];
  const float* w_hh0  = (const float*)d_in[3];
  const float* b_ih0  = (const float*)d_in[4];
  const float* b_hh0  = (const float*)d_in[5];
  const float* w_ih1  = (const float*)d_in[6];
  const float* w_hh1  = (const float*)d_in[7];
  const float* b_ih1  = (const float*)d_in[8];
  const float* b_hh1  = (const float*)d_in[9];
  const float* fc_w   = (const float*)d_in[10];
  const float* fc_b   = (const float*)d_in[11];
  float* out = (float*)d_out;

  // ws: [0,4096) barrier counters; h0 frag dbuf 256KB; h1 frag dbuf 256KB
  unsigned* bar = (unsigned*)d_ws;
  unsigned short* h0f = (unsigned short*)((char*)d_ws + 4096);
  unsigned short* h1f = h0f + 2 * NG * (16 * 64 * 8);

  hipMemsetAsync(d_ws, 0, 4096, stream);

  rnn_mfma<<<dim3(NBLK), dim3(256), 0, stream>>>(
      x, h0init, w_ih0, w_hh0, b_ih0, b_hh0, w_ih1, w_hh1, b_ih1, b_hh1,
      fc_w, fc_b, out, bar, h0f, h1f);
}